// Round 2
// baseline (397.231 us; speedup 1.0000x reference)
//
#include <hip/hip_runtime.h>
#include <hip/hip_bf16.h>

using bf16 = __hip_bfloat16;
typedef unsigned int u32x4 __attribute__((ext_vector_type(4)));
typedef float f32x4 __attribute__((ext_vector_type(4)));
typedef __bf16 bf16x8 __attribute__((ext_vector_type(8)));

#define DEVI __device__ __forceinline__

DEVI f32x4 mfma16(u32x4 a, u32x4 b, f32x4 c) {
    return __builtin_amdgcn_mfma_f32_16x16x32_bf16(
        __builtin_bit_cast(bf16x8, a), __builtin_bit_cast(bf16x8, b), c, 0, 0, 0);
}

struct bf8 { bf16 h[8]; };

DEVI u32x4 pack8(f32x4 lo, f32x4 hi) {
    bf8 t;
#pragma unroll
    for (int i = 0; i < 4; i++) {
        t.h[i] = __float2bfloat16(lo[i]);
        t.h[4 + i] = __float2bfloat16(hi[i]);
    }
    return __builtin_bit_cast(u32x4, t);
}

// ------------- weight prep: WT[n][k] = (bf16)W[k][n], 5 matrices 512x512 -----
__global__ __launch_bounds__(256) void prep_weights(
    const float* __restrict__ Wq, const float* __restrict__ Wk,
    const float* __restrict__ Wv, const float* __restrict__ W1,
    const float* __restrict__ W2, bf16* __restrict__ WT)
{
    int w = blockIdx.y;
    const float* src = (w == 0) ? Wq : (w == 1) ? Wk : (w == 2) ? Wv : (w == 3) ? W1 : W2;
    int idx = blockIdx.x * 256 + threadIdx.x;   // idx = n*512 + k
    int n = idx >> 9, kk = idx & 511;
    WT[(size_t)w * 262144 + idx] = __float2bfloat16(src[kk * 512 + n]);
}

// ------------- GEMM: C[M x 512] = A[M x 512] @ W (given bf16 W^T) + bias -----
enum { EPI_NONE = 0, EPI_RELU = 1, EPI_VT = 2 };

template <int EPI, bool AF32>
__global__ __launch_bounds__(256) void gemm_bt(
    const void* __restrict__ Av, const bf16* __restrict__ Bt,
    const float* __restrict__ bias, bf16* __restrict__ C)
{
    __shared__ __align__(16) bf16 As[128 * 32];
    __shared__ __align__(16) bf16 Bs[128 * 32];
    const int tid = threadIdx.x;
    const int lane = tid & 63, wave = tid >> 6;
    const int wm = (wave >> 1) * 64, wn = (wave & 1) * 64;
    const int bm = blockIdx.x * 128, bn = blockIdx.y * 128;
    const int lm = lane & 15, lq = lane >> 4;

    f32x4 acc[4][4];
#pragma unroll
    for (int i = 0; i < 4; i++)
#pragma unroll
        for (int j = 0; j < 4; j++) acc[i][j] = (f32x4){0.f, 0.f, 0.f, 0.f};

    for (int k0 = 0; k0 < 512; k0 += 32) {
#pragma unroll
        for (int p = 0; p < 2; p++) {
            int c = p * 256 + tid;
            int r = c >> 2, kc = (c & 3) * 8;
            if (AF32) {
                const float* Af = (const float*)Av;
                f32x4 lo = *(const f32x4*)&Af[(size_t)(bm + r) * 512 + k0 + kc];
                f32x4 hi = *(const f32x4*)&Af[(size_t)(bm + r) * 512 + k0 + kc + 4];
                *(u32x4*)&As[r * 32 + kc] = pack8(lo, hi);
            } else {
                const bf16* Ah = (const bf16*)Av;
                *(u32x4*)&As[r * 32 + kc] = *(const u32x4*)&Ah[(size_t)(bm + r) * 512 + k0 + kc];
            }
            *(u32x4*)&Bs[r * 32 + kc] = *(const u32x4*)&Bt[(size_t)(bn + r) * 512 + k0 + kc];
        }
        __syncthreads();
        u32x4 af[4], bfr[4];
#pragma unroll
        for (int i = 0; i < 4; i++) af[i] = *(const u32x4*)&As[(wm + i * 16 + lm) * 32 + lq * 8];
#pragma unroll
        for (int j = 0; j < 4; j++) bfr[j] = *(const u32x4*)&Bs[(wn + j * 16 + lm) * 32 + lq * 8];
#pragma unroll
        for (int i = 0; i < 4; i++)
#pragma unroll
            for (int j = 0; j < 4; j++) acc[i][j] = mfma16(af[i], bfr[j], acc[i][j]);
        __syncthreads();
    }

#pragma unroll
    for (int i = 0; i < 4; i++) {
#pragma unroll
        for (int j = 0; j < 4; j++) {
            int col = bn + wn + j * 16 + lm;
            float bv = bias[col];
#pragma unroll
            for (int r = 0; r < 4; r++) {
                int row = bm + wm + i * 16 + lq * 4 + r;
                float cv = acc[i][j][r] + bv;
                if (EPI == EPI_RELU) cv = fmaxf(cv, 0.f);
                if (EPI == EPI_VT) {
                    int bt = row >> 10, node = row & 1023;
                    int hh = col >> 6, d = col & 63;
                    C[((size_t)((bt * 8 + hh) * 64 + d)) * 1024 + node] = __float2bfloat16(cv);
                } else {
                    C[(size_t)row * 512 + col] = __float2bfloat16(cv);
                }
            }
        }
    }
}

// ------------- flash attention: per (bt,h) group, 128-row q-tiles ------------
// q,k: [16384 x 512] bf16 ; vT: [(bt*8+h)*64+d][1024 nodes] bf16 ; o: f32
__global__ __launch_bounds__(256) void attn_kernel(
    const bf16* __restrict__ q, const bf16* __restrict__ k,
    const bf16* __restrict__ vT, float* __restrict__ o)
{
    constexpr int KP = 72;    // 64 + 8 pad
    constexpr int VP = 136;   // 128 + 8 pad
    // Ks (128x72 = 9216 el) and Ps (4x32x136 = 17408 el) share one buffer
    __shared__ __align__(16) bf16 KsPs[4 * 32 * VP];
    __shared__ __align__(16) bf16 Vs[64 * VP];

    const int tid = threadIdx.x, lane = tid & 63, wave = tid >> 6;
    const int group = blockIdx.y;          // bt*8 + h
    const int bt = group >> 3, hh = group & 7;
    const int qt = blockIdx.x;
    const int lm = lane & 15, lq = lane >> 4;
    const int qrow0 = bt * 1024 + qt * 128 + wave * 32;

    u32x4 qf[2][2];
#pragma unroll
    for (int tm = 0; tm < 2; tm++)
#pragma unroll
        for (int kk = 0; kk < 2; kk++)
            qf[tm][kk] = *(const u32x4*)&q[(size_t)(qrow0 + tm * 16 + lm) * 512 + hh * 64 + kk * 32 + lq * 8];

    f32x4 accO[2][4];
#pragma unroll
    for (int tm = 0; tm < 2; tm++)
#pragma unroll
        for (int tn = 0; tn < 4; tn++) accO[tm][tn] = (f32x4){0.f, 0.f, 0.f, 0.f};
    float m_run[2][4], l_run[2][4];
#pragma unroll
    for (int tm = 0; tm < 2; tm++)
#pragma unroll
        for (int r = 0; r < 4; r++) { m_run[tm][r] = -1e30f; l_run[tm][r] = 0.f; }

    for (int kt = 0; kt < 8; kt++) {
        __syncthreads();   // prior iteration's PV reads of KsPs/Vs complete
        // stage K tile (128 keys x 64 d) into KsPs and V^T tile into Vs
#pragma unroll
        for (int p = 0; p < 4; p++) {
            int c = p * 256 + tid;
            {
                int key = c >> 3, dc = (c & 7) * 8;
                *(u32x4*)&KsPs[key * KP + dc] =
                    *(const u32x4*)&k[(size_t)(bt * 1024 + kt * 128 + key) * 512 + hh * 64 + dc];
            }
            {
                int d = c >> 4, kc = (c & 15) * 8;
                *(u32x4*)&Vs[d * VP + kc] =
                    *(const u32x4*)&vT[(size_t)(group * 64 + d) * 1024 + kt * 128 + kc];
            }
        }
        __syncthreads();

        // S = Q K^T  (wave's 32 q-rows x 128 keys)
        f32x4 s[2][8];
#pragma unroll
        for (int tn = 0; tn < 8; tn++) {
            u32x4 kf0 = *(const u32x4*)&KsPs[(tn * 16 + lm) * KP + lq * 8];
            u32x4 kf1 = *(const u32x4*)&KsPs[(tn * 16 + lm) * KP + 32 + lq * 8];
#pragma unroll
            for (int tm = 0; tm < 2; tm++) {
                f32x4 t = (f32x4){0.f, 0.f, 0.f, 0.f};
                t = mfma16(qf[tm][0], kf0, t);
                t = mfma16(qf[tm][1], kf1, t);
                s[tm][tn] = t;
            }
        }
        __syncthreads();   // all S reads of Ks view done before P overwrites
#pragma unroll
        for (int tm = 0; tm < 2; tm++)
#pragma unroll
            for (int tn = 0; tn < 8; tn++) s[tm][tn] *= 0.125f;   // 1/sqrt(64)

        bf16* Ps = &KsPs[wave * 32 * VP];
#pragma unroll
        for (int tm = 0; tm < 2; tm++) {
            float alpha[4];
#pragma unroll
            for (int r = 0; r < 4; r++) {
                float mx = -1e30f;
#pragma unroll
                for (int tn = 0; tn < 8; tn++) mx = fmaxf(mx, s[tm][tn][r]);
#pragma unroll
                for (int off = 1; off < 16; off <<= 1) mx = fmaxf(mx, __shfl_xor(mx, off));
                float mnew = fmaxf(m_run[tm][r], mx);
                alpha[r] = exp2f((m_run[tm][r] - mnew) * 1.44269504f);
                m_run[tm][r] = mnew;
            }
            float rs[4] = {0.f, 0.f, 0.f, 0.f};
#pragma unroll
            for (int tn = 0; tn < 8; tn++)
#pragma unroll
                for (int r = 0; r < 4; r++) {
                    float p = exp2f((s[tm][tn][r] - m_run[tm][r]) * 1.44269504f);
                    rs[r] += p;
                    Ps[(tm * 16 + lq * 4 + r) * VP + tn * 16 + lm] = __float2bfloat16(p);
                }
#pragma unroll
            for (int r = 0; r < 4; r++) {
#pragma unroll
                for (int off = 1; off < 16; off <<= 1) rs[r] += __shfl_xor(rs[r], off);
                l_run[tm][r] = l_run[tm][r] * alpha[r] + rs[r];
#pragma unroll
                for (int tn = 0; tn < 4; tn++) accO[tm][tn][r] *= alpha[r];
            }
        }
        __syncthreads();   // P visible before A-frag reads

        // O += P V
#pragma unroll
        for (int kc = 0; kc < 4; kc++) {
            u32x4 pf[2], vf[4];
#pragma unroll
            for (int tm = 0; tm < 2; tm++)
                pf[tm] = *(const u32x4*)&Ps[(tm * 16 + lm) * VP + kc * 32 + lq * 8];
#pragma unroll
            for (int tn = 0; tn < 4; tn++)
                vf[tn] = *(const u32x4*)&Vs[(tn * 16 + lm) * VP + kc * 32 + lq * 8];
#pragma unroll
            for (int tm = 0; tm < 2; tm++)
#pragma unroll
                for (int tn = 0; tn < 4; tn++)
                    accO[tm][tn] = mfma16(pf[tm], vf[tn], accO[tm][tn]);
        }
    }

    // write O (normalized) as f32
#pragma unroll
    for (int tm = 0; tm < 2; tm++)
#pragma unroll
        for (int tn = 0; tn < 4; tn++)
#pragma unroll
            for (int r = 0; r < 4; r++) {
                int row = qrow0 + tm * 16 + lq * 4 + r;
                int col = hh * 64 + tn * 16 + lm;
                o[(size_t)row * 512 + col] = accO[tm][tn][r] / l_run[tm][r];
            }
}

// ------------- LayerNorm (one wave per 512-el row) ---------------------------
// AF32: main input dtype; RES: add f32 residual; OF32: output dtype
template <bool AF32, bool RES, bool OF32>
__global__ __launch_bounds__(256) void ln_kernel(
    const void* __restrict__ a, const float* __restrict__ res,
    const float* __restrict__ g, const float* __restrict__ bb, void* __restrict__ out)
{
    int row = blockIdx.x * 4 + (threadIdx.x >> 6);
    int lane = threadIdx.x & 63;
    size_t base = (size_t)row * 512 + lane * 8;
    int cbase = lane * 8;

    float x8[8];
    if (AF32) {
        const float* af = (const float*)a;
        f32x4 lo = *(const f32x4*)&af[base];
        f32x4 hi = *(const f32x4*)&af[base + 4];
#pragma unroll
        for (int i = 0; i < 4; i++) { x8[i] = lo[i]; x8[4 + i] = hi[i]; }
    } else {
        bf8 av = __builtin_bit_cast(bf8, *(const u32x4*)&((const bf16*)a)[base]);
#pragma unroll
        for (int i = 0; i < 8; i++) x8[i] = __bfloat162float(av.h[i]);
    }
    if (RES) {
        f32x4 lo = *(const f32x4*)&res[base];
        f32x4 hi = *(const f32x4*)&res[base + 4];
#pragma unroll
        for (int i = 0; i < 4; i++) { x8[i] += lo[i]; x8[4 + i] += hi[i]; }
    }

    float s = 0.f, s2 = 0.f;
#pragma unroll
    for (int i = 0; i < 8; i++) { s += x8[i]; s2 += x8[i] * x8[i]; }
#pragma unroll
    for (int off = 1; off < 64; off <<= 1) {
        s += __shfl_xor(s, off);
        s2 += __shfl_xor(s2, off);
    }
    float mean = s * (1.f / 512.f);
    float var = s2 * (1.f / 512.f) - mean * mean;
    float rstd = rsqrtf(var + 1e-5f);

    f32x4 g0 = *(const f32x4*)&g[cbase], g1 = *(const f32x4*)&g[cbase + 4];
    f32x4 b0 = *(const f32x4*)&bb[cbase], b1v = *(const f32x4*)&bb[cbase + 4];
    float y[8];
#pragma unroll
    for (int i = 0; i < 4; i++) {
        y[i] = (x8[i] - mean) * rstd * g0[i] + b0[i];
        y[4 + i] = (x8[4 + i] - mean) * rstd * g1[i] + b1v[i];
    }
    if (OF32) {
        float* op = (float*)out;
        *(f32x4*)&op[base] = (f32x4){y[0], y[1], y[2], y[3]};
        *(f32x4*)&op[base + 4] = (f32x4){y[4], y[5], y[6], y[7]};
    } else {
        bf8 ov;
#pragma unroll
        for (int i = 0; i < 8; i++) ov.h[i] = __float2bfloat16(y[i]);
        *(u32x4*)&((bf16*)out)[base] = __builtin_bit_cast(u32x4, ov);
    }
}

// ------------- launch --------------------------------------------------------
extern "C" void kernel_launch(void* const* d_in, const int* in_sizes, int n_in,
                              void* d_out, int out_size, void* d_ws, size_t ws_size,
                              hipStream_t stream)
{
    const float* x    = (const float*)d_in[0];
    const float* Wq   = (const float*)d_in[1];
    const float* bq   = (const float*)d_in[2];
    const float* Wk   = (const float*)d_in[3];
    const float* bk   = (const float*)d_in[4];
    const float* Wv   = (const float*)d_in[5];
    const float* bv   = (const float*)d_in[6];
    const float* ln_g = (const float*)d_in[7];
    const float* ln_b = (const float*)d_in[8];
    const float* W1   = (const float*)d_in[9];
    const float* b1   = (const float*)d_in[10];
    const float* W2   = (const float*)d_in[11];
    const float* b2   = (const float*)d_in[12];
    const float* lnffg = (const float*)d_in[13];
    const float* lnffb = (const float*)d_in[14];
    float* out = (float*)d_out;

    bf16* ws = (bf16*)d_ws;
    bf16* WT = ws;                        // 5 * 262144 bf16
    bf16* qb = ws + 5 * 262144;           // 8388608 bf16 each below
    bf16* kb = qb + 8388608;
    bf16* vT = kb + 8388608;
    bf16* vl = qb;                        // reuse (q dead after attention)
    bf16* f1 = kb;                        // reuse (k dead after attention)
    bf16* f2 = vT;                        // reuse (v dead after attention)

    prep_weights<<<dim3(1024, 5), 256, 0, stream>>>(Wq, Wk, Wv, W1, W2, WT);

    dim3 gg(128, 4);
    gemm_bt<EPI_NONE, true><<<gg, 256, 0, stream>>>(x, WT + 0 * 262144, bq, qb);
    gemm_bt<EPI_NONE, true><<<gg, 256, 0, stream>>>(x, WT + 1 * 262144, bk, kb);
    gemm_bt<EPI_VT,   true><<<gg, 256, 0, stream>>>(x, WT + 2 * 262144, bv, vT);

    attn_kernel<<<dim3(8, 128), 256, 0, stream>>>(qb, kb, vT, out);

    ln_kernel<true, true, false><<<4096, 256, 0, stream>>>(out, x, ln_g, ln_b, vl);

    gemm_bt<EPI_RELU, false><<<gg, 256, 0, stream>>>(vl, WT + 3 * 262144, b1, f1);
    gemm_bt<EPI_NONE, false><<<gg, 256, 0, stream>>>(f1, WT + 4 * 262144, b2, f2);

    ln_kernel<false, false, true><<<4096, 256, 0, stream>>>(f2, nullptr, lnffg, lnffb, out);
}

// Round 4
// 288.230 us; speedup vs baseline: 1.3782x; 1.3782x over previous
//
#include <hip/hip_runtime.h>
#include <hip/hip_bf16.h>

using bf16 = __hip_bfloat16;
typedef unsigned int u32x4 __attribute__((ext_vector_type(4)));
typedef float f32x4 __attribute__((ext_vector_type(4)));
typedef __bf16 bf16x8 __attribute__((ext_vector_type(8)));

#define DEVI __device__ __forceinline__

DEVI f32x4 mfma16(u32x4 a, u32x4 b, f32x4 c) {
    return __builtin_amdgcn_mfma_f32_16x16x32_bf16(
        __builtin_bit_cast(bf16x8, a), __builtin_bit_cast(bf16x8, b), c, 0, 0, 0);
}

struct bf8 { bf16 h[8]; };

DEVI u32x4 pack8(f32x4 lo, f32x4 hi) {
    bf8 t;
#pragma unroll
    for (int i = 0; i < 4; i++) {
        t.h[i] = __float2bfloat16(lo[i]);
        t.h[4 + i] = __float2bfloat16(hi[i]);
    }
    return __builtin_bit_cast(u32x4, t);
}

// async 16B global->LDS (m97 pattern: wave-uniform LDS base + lane*16)
DEVI void async16(const bf16* g, bf16* l) {
    __builtin_amdgcn_global_load_lds(
        (const __attribute__((address_space(1))) unsigned int*)g,
        (__attribute__((address_space(3))) unsigned int*)l, 16, 0, 0);
}

// ------------- weight prep: WT[n][k] = (bf16)W[k][n], 5 matrices 512x512 -----
__global__ __launch_bounds__(256) void prep_weights(
    const float* __restrict__ Wq, const float* __restrict__ Wk,
    const float* __restrict__ Wv, const float* __restrict__ W1,
    const float* __restrict__ W2, bf16* __restrict__ WT)
{
    int w = blockIdx.y;
    const float* src = (w == 0) ? Wq : (w == 1) ? Wk : (w == 2) ? Wv : (w == 3) ? W1 : W2;
    int idx = blockIdx.x * 256 + threadIdx.x;   // idx = n*512 + k
    int n = idx >> 9, kk = idx & 511;
    WT[(size_t)w * 262144 + idx] = __float2bfloat16(src[kk * 512 + n]);
}

// ------------- x prep: bf16 copy of x (into d_out scratch) -------------------
// 8,388,608 elements = 4096 blocks * 256 threads * 8 el   (8192 was OOB 2x!)
__global__ __launch_bounds__(256) void prep_x(const float* __restrict__ x, bf16* __restrict__ xb)
{
    size_t i = ((size_t)blockIdx.x * 256 + threadIdx.x) * 8;
    f32x4 lo = *(const f32x4*)&x[i];
    f32x4 hi = *(const f32x4*)&x[i + 4];
    *(u32x4*)&xb[i] = pack8(lo, hi);
}

// ------------- GEMM: C[M x 512] = A[M x 512] @ W (given bf16 W^T) + bias -----
enum { EPI_NONE = 0, EPI_RELU = 1, EPI_VT = 2, EPI_SCALE = 3 };

template <int EPI>
__global__ __launch_bounds__(256) void gemm_bt(
    const bf16* __restrict__ A, const bf16* __restrict__ Bt,
    const float* __restrict__ bias, bf16* __restrict__ C)
{
    __shared__ __align__(16) bf16 As[128 * 32];
    __shared__ __align__(16) bf16 Bs[128 * 32];
    const int tid = threadIdx.x;
    const int lane = tid & 63, wave = tid >> 6;
    const int wm = (wave >> 1) * 64, wn = (wave & 1) * 64;
    const int bm = blockIdx.x * 128, bn = blockIdx.y * 128;
    const int lm = lane & 15, lq = lane >> 4;

    f32x4 acc[4][4];
#pragma unroll
    for (int i = 0; i < 4; i++)
#pragma unroll
        for (int j = 0; j < 4; j++) acc[i][j] = (f32x4){0.f, 0.f, 0.f, 0.f};

    for (int k0 = 0; k0 < 512; k0 += 32) {
        __syncthreads();   // prior frag reads complete before overwrite
#pragma unroll
        for (int p = 0; p < 2; p++) {
            int c = p * 256 + tid;
            int r = c >> 2, kc = (c & 3) * 8;
            // LDS el offset = c*8 (lane-contiguous); base uniform per wave
            async16(&A[(size_t)(bm + r) * 512 + k0 + kc], &As[(p * 256 + wave * 64) * 8]);
            async16(&Bt[(size_t)(bn + r) * 512 + k0 + kc], &Bs[(p * 256 + wave * 64) * 8]);
        }
        __syncthreads();   // drains vmcnt(0): LDS valid
        u32x4 af[4], bfr[4];
#pragma unroll
        for (int i = 0; i < 4; i++) af[i] = *(const u32x4*)&As[(wm + i * 16 + lm) * 32 + lq * 8];
#pragma unroll
        for (int j = 0; j < 4; j++) bfr[j] = *(const u32x4*)&Bs[(wn + j * 16 + lm) * 32 + lq * 8];
#pragma unroll
        for (int i = 0; i < 4; i++)
#pragma unroll
            for (int j = 0; j < 4; j++) acc[i][j] = mfma16(af[i], bfr[j], acc[i][j]);
    }

#pragma unroll
    for (int i = 0; i < 4; i++) {
#pragma unroll
        for (int j = 0; j < 4; j++) {
            int col = bn + wn + j * 16 + lm;
            float bv = bias[col];
#pragma unroll
            for (int r = 0; r < 4; r++) {
                int row = bm + wm + i * 16 + lq * 4 + r;
                float cv = acc[i][j][r] + bv;
                if (EPI == EPI_RELU) cv = fmaxf(cv, 0.f);
                if (EPI == EPI_SCALE) cv *= 0.18033688f;   // log2(e)/8 folded into q
                if (EPI == EPI_VT) {
                    int bt = row >> 10, node = row & 1023;
                    int hh = col >> 6, d = col & 63;
                    C[((size_t)((bt * 8 + hh) * 64 + d)) * 1024 + node] = __float2bfloat16(cv);
                } else {
                    C[(size_t)row * 512 + col] = __float2bfloat16(cv);
                }
            }
        }
    }
}

// ------------- flash attention (no-max softmax, S^T trick) -------------------
// q (pre-scaled by log2e/8), k: [16384 x 512] bf16 ; vT: [(g)*64+d][1024] bf16
// o: [16384 x 512] f32
__global__ __launch_bounds__(256) void attn_kernel(
    const bf16* __restrict__ q, const bf16* __restrict__ k,
    const bf16* __restrict__ vT, float* __restrict__ o)
{
    constexpr int KP = 72;   // Ks row stride el (144 B, 16-aligned)
    constexpr int VP = 80;   // Vs/Ps row stride el (160 B, 16-aligned; 76 was misaligned for b128!)
    __shared__ __align__(16) bf16 Ks[64 * KP];        // [key][d]
    __shared__ __align__(16) bf16 Vs[64 * VP];        // [d][key]
    __shared__ __align__(16) bf16 Ps[4][32 * VP];     // per-wave [q][key]

    const int tid = threadIdx.x, lane = tid & 63, wave = tid >> 6;
    const int group = blockIdx.y;          // bt*8 + h
    const int bt = group >> 3, hh = group & 7;
    const int lm = lane & 15, lq = lane >> 4;
    const int qrow0 = bt * 1024 + blockIdx.x * 128 + wave * 32;

    u32x4 qf[2][2];
#pragma unroll
    for (int tm = 0; tm < 2; tm++)
#pragma unroll
        for (int kk = 0; kk < 2; kk++)
            qf[tm][kk] = *(const u32x4*)&q[(size_t)(qrow0 + tm * 16 + lm) * 512 + hh * 64 + kk * 32 + lq * 8];

    f32x4 accO[2][4];
#pragma unroll
    for (int tm = 0; tm < 2; tm++)
#pragma unroll
        for (int tn = 0; tn < 4; tn++) accO[tm][tn] = (f32x4){0.f, 0.f, 0.f, 0.f};
    float part[2] = {0.f, 0.f};

    for (int kt = 0; kt < 16; kt++) {
        __syncthreads();   // prior S/PV reads of Ks/Vs done
#pragma unroll
        for (int p = 0; p < 2; p++) {
            int c = p * 256 + tid;
            int row = c >> 3, e8 = (c & 7) * 8;
            *(u32x4*)&Ks[row * KP + e8] =
                *(const u32x4*)&k[(size_t)(bt * 1024 + kt * 64 + row) * 512 + hh * 64 + e8];
            *(u32x4*)&Vs[row * VP + e8] =
                *(const u32x4*)&vT[(size_t)(group * 64 + row) * 1024 + kt * 64 + e8];
        }
        __syncthreads();

        // S^T tiles: A=K (m=key), B=Q (n=q); C-frag rows = 4 consecutive keys
#pragma unroll
        for (int tk = 0; tk < 4; tk++) {
            u32x4 kf0 = *(const u32x4*)&Ks[(tk * 16 + lm) * KP + lq * 8];
            u32x4 kf1 = *(const u32x4*)&Ks[(tk * 16 + lm) * KP + 32 + lq * 8];
#pragma unroll
            for (int tm = 0; tm < 2; tm++) {
                f32x4 st = (f32x4){0.f, 0.f, 0.f, 0.f};
                st = mfma16(kf0, qf[tm][0], st);
                st = mfma16(kf1, qf[tm][1], st);
                float p0 = exp2f(st[0]), p1 = exp2f(st[1]);
                float p2 = exp2f(st[2]), p3 = exp2f(st[3]);
                part[tm] += (p0 + p1) + (p2 + p3);
                union { unsigned long long u; bf16 h[4]; } pk;
                pk.h[0] = __float2bfloat16(p0); pk.h[1] = __float2bfloat16(p1);
                pk.h[2] = __float2bfloat16(p2); pk.h[3] = __float2bfloat16(p3);
                // P[q=tm*16+lm][key=tk*16+lq*4 .. +3]  (wave-private, no barrier)
                *(unsigned long long*)&Ps[wave][(tm * 16 + lm) * VP + tk * 16 + lq * 4] = pk.u;
            }
        }

        // O += P V   (A=P from LDS, B=V^T)
#pragma unroll
        for (int kc = 0; kc < 2; kc++) {
            u32x4 pf[2], vf[4];
#pragma unroll
            for (int tm = 0; tm < 2; tm++)
                pf[tm] = *(const u32x4*)&Ps[wave][(tm * 16 + lm) * VP + kc * 32 + lq * 8];
#pragma unroll
            for (int tn = 0; tn < 4; tn++)
                vf[tn] = *(const u32x4*)&Vs[(tn * 16 + lm) * VP + kc * 32 + lq * 8];
#pragma unroll
            for (int tm = 0; tm < 2; tm++)
#pragma unroll
                for (int tn = 0; tn < 4; tn++)
                    accO[tm][tn] = mfma16(pf[tm], vf[tn], accO[tm][tn]);
        }
    }

    // final l reduction (across quads) and normalized store
#pragma unroll
    for (int tm = 0; tm < 2; tm++) {
        part[tm] += __shfl_xor(part[tm], 16);
        part[tm] += __shfl_xor(part[tm], 32);
    }
#pragma unroll
    for (int tm = 0; tm < 2; tm++)
#pragma unroll
        for (int r = 0; r < 4; r++) {
            float l = __shfl(part[tm], lq * 4 + r);   // lane lq*4+r holds l for q-row lq*4+r
            float linv = 1.0f / l;
#pragma unroll
            for (int tn = 0; tn < 4; tn++) {
                int row = qrow0 + tm * 16 + lq * 4 + r;
                int col = hh * 64 + tn * 16 + lm;
                o[(size_t)row * 512 + col] = accO[tm][tn][r] * linv;
            }
        }
}

// ------------- LayerNorm (one wave per 512-el row) ---------------------------
template <bool AF32, bool RES, bool OF32>
__global__ __launch_bounds__(256) void ln_kernel(
    const void* __restrict__ a, const float* __restrict__ res,
    const float* __restrict__ g, const float* __restrict__ bb, void* __restrict__ out)
{
    int row = blockIdx.x * 4 + (threadIdx.x >> 6);
    int lane = threadIdx.x & 63;
    size_t base = (size_t)row * 512 + lane * 8;
    int cbase = lane * 8;

    float x8[8];
    if (AF32) {
        const float* af = (const float*)a;
        f32x4 lo = *(const f32x4*)&af[base];
        f32x4 hi = *(const f32x4*)&af[base + 4];
#pragma unroll
        for (int i = 0; i < 4; i++) { x8[i] = lo[i]; x8[4 + i] = hi[i]; }
    } else {
        bf8 av = __builtin_bit_cast(bf8, *(const u32x4*)&((const bf16*)a)[base]);
#pragma unroll
        for (int i = 0; i < 8; i++) x8[i] = __bfloat162float(av.h[i]);
    }
    if (RES) {
        f32x4 lo = *(const f32x4*)&res[base];
        f32x4 hi = *(const f32x4*)&res[base + 4];
#pragma unroll
        for (int i = 0; i < 4; i++) { x8[i] += lo[i]; x8[4 + i] += hi[i]; }
    }

    float s = 0.f, s2 = 0.f;
#pragma unroll
    for (int i = 0; i < 8; i++) { s += x8[i]; s2 += x8[i] * x8[i]; }
#pragma unroll
    for (int off = 1; off < 64; off <<= 1) {
        s += __shfl_xor(s, off);
        s2 += __shfl_xor(s2, off);
    }
    float mean = s * (1.f / 512.f);
    float var = s2 * (1.f / 512.f) - mean * mean;
    float rstd = rsqrtf(var + 1e-5f);

    f32x4 g0 = *(const f32x4*)&g[cbase], g1 = *(const f32x4*)&g[cbase + 4];
    f32x4 b0 = *(const f32x4*)&bb[cbase], b1v = *(const f32x4*)&bb[cbase + 4];
    float y[8];
#pragma unroll
    for (int i = 0; i < 4; i++) {
        y[i] = (x8[i] - mean) * rstd * g0[i] + b0[i];
        y[4 + i] = (x8[4 + i] - mean) * rstd * g1[i] + b1v[i];
    }
    if (OF32) {
        float* op = (float*)out;
        *(f32x4*)&op[base] = (f32x4){y[0], y[1], y[2], y[3]};
        *(f32x4*)&op[base + 4] = (f32x4){y[4], y[5], y[6], y[7]};
    } else {
        bf8 ov;
#pragma unroll
        for (int i = 0; i < 8; i++) ov.h[i] = __float2bfloat16(y[i]);
        *(u32x4*)&((bf16*)out)[base] = __builtin_bit_cast(u32x4, ov);
    }
}

// ------------- launch --------------------------------------------------------
extern "C" void kernel_launch(void* const* d_in, const int* in_sizes, int n_in,
                              void* d_out, int out_size, void* d_ws, size_t ws_size,
                              hipStream_t stream)
{
    const float* x    = (const float*)d_in[0];
    const float* Wq   = (const float*)d_in[1];
    const float* bq   = (const float*)d_in[2];
    const float* Wk   = (const float*)d_in[3];
    const float* bk   = (const float*)d_in[4];
    const float* Wv   = (const float*)d_in[5];
    const float* bv   = (const float*)d_in[6];
    const float* ln_g = (const float*)d_in[7];
    const float* ln_b = (const float*)d_in[8];
    const float* W1   = (const float*)d_in[9];
    const float* b1   = (const float*)d_in[10];
    const float* W2   = (const float*)d_in[11];
    const float* b2   = (const float*)d_in[12];
    const float* lnffg = (const float*)d_in[13];
    const float* lnffb = (const float*)d_in[14];
    float* out = (float*)d_out;

    bf16* ws = (bf16*)d_ws;
    bf16* WT = ws;                        // 5 * 262144 bf16
    bf16* qb = ws + 5 * 262144;           // 8388608 bf16 each below
    bf16* kb = qb + 8388608;
    bf16* vT = kb + 8388608;
    bf16* vl = qb;                        // reuse (q dead after attention)
    bf16* f1 = kb;                        // reuse (k dead after attention)
    bf16* f2 = vT;                        // reuse (v dead after attention)
    bf16* xb = (bf16*)d_out;              // 8388608 bf16 = 16.7MB, fits 33.5MB; dead before attention writes O

    prep_weights<<<dim3(1024, 5), 256, 0, stream>>>(Wq, Wk, Wv, W1, W2, WT);
    prep_x<<<4096, 256, 0, stream>>>(x, xb);

    dim3 gg(128, 4);
    gemm_bt<EPI_SCALE><<<gg, 256, 0, stream>>>(xb, WT + 0 * 262144, bq, qb);
    gemm_bt<EPI_NONE> <<<gg, 256, 0, stream>>>(xb, WT + 1 * 262144, bk, kb);
    gemm_bt<EPI_VT>   <<<gg, 256, 0, stream>>>(xb, WT + 2 * 262144, bv, vT);

    attn_kernel<<<dim3(8, 128), 256, 0, stream>>>(qb, kb, vT, out);

    ln_kernel<true, true, false><<<4096, 256, 0, stream>>>(out, x, ln_g, ln_b, vl);

    gemm_bt<EPI_RELU><<<gg, 256, 0, stream>>>(vl, WT + 3 * 262144, b1, f1);
    gemm_bt<EPI_NONE><<<gg, 256, 0, stream>>>(f1, WT + 4 * 262144, b2, f2);

    ln_kernel<false, false, true><<<4096, 256, 0, stream>>>(f2, nullptr, lnffg, lnffb, out);
}

// Round 5
// 278.501 us; speedup vs baseline: 1.4263x; 1.0349x over previous
//
#include <hip/hip_runtime.h>
#include <hip/hip_bf16.h>

using bf16 = __hip_bfloat16;
typedef unsigned int u32x4 __attribute__((ext_vector_type(4)));
typedef float f32x4 __attribute__((ext_vector_type(4)));
typedef __bf16 bf16x8 __attribute__((ext_vector_type(8)));

#define DEVI __device__ __forceinline__

DEVI f32x4 mfma16(u32x4 a, u32x4 b, f32x4 c) {
    return __builtin_amdgcn_mfma_f32_16x16x32_bf16(
        __builtin_bit_cast(bf16x8, a), __builtin_bit_cast(bf16x8, b), c, 0, 0, 0);
}

struct bf8 { bf16 h[8]; };

DEVI u32x4 pack8(f32x4 lo, f32x4 hi) {
    bf8 t;
#pragma unroll
    for (int i = 0; i < 4; i++) {
        t.h[i] = __float2bfloat16(lo[i]);
        t.h[4 + i] = __float2bfloat16(hi[i]);
    }
    return __builtin_bit_cast(u32x4, t);
}

// RNE bf16x2 pack, no NaN path (inputs are finite positive): ~5 VALU for 2 vals
DEVI unsigned rne2(float a, float b) {
    unsigned ua = __builtin_bit_cast(unsigned, a);
    unsigned ub = __builtin_bit_cast(unsigned, b);
    ua += 0x7FFFu + ((ua >> 16) & 1u);
    ub += 0x7FFFu + ((ub >> 16) & 1u);
    return __builtin_amdgcn_perm(ub, ua, 0x07060302);  // [ua.hi16 | ub.hi16<<16]
}

// async 16B global->LDS (m97 pattern: wave-uniform LDS base + lane*16)
DEVI void async16(const bf16* g, bf16* l) {
    __builtin_amdgcn_global_load_lds(
        (const __attribute__((address_space(1))) unsigned int*)g,
        (__attribute__((address_space(3))) unsigned int*)l, 16, 0, 0);
}

// ------------- weight prep: WT[n][k] = (bf16)W[k][n], 5 matrices 512x512 -----
__global__ __launch_bounds__(256) void prep_weights(
    const float* __restrict__ Wq, const float* __restrict__ Wk,
    const float* __restrict__ Wv, const float* __restrict__ W1,
    const float* __restrict__ W2, bf16* __restrict__ WT)
{
    int w = blockIdx.y;
    const float* src = (w == 0) ? Wq : (w == 1) ? Wk : (w == 2) ? Wv : (w == 3) ? W1 : W2;
    int idx = blockIdx.x * 256 + threadIdx.x;   // idx = n*512 + k
    int n = idx >> 9, kk = idx & 511;
    WT[(size_t)w * 262144 + idx] = __float2bfloat16(src[kk * 512 + n]);
}

// ------------- x prep: bf16 copy of x (into d_out scratch) -------------------
__global__ __launch_bounds__(256) void prep_x(const float* __restrict__ x, bf16* __restrict__ xb)
{
    size_t i = ((size_t)blockIdx.x * 256 + threadIdx.x) * 8;
    f32x4 lo = *(const f32x4*)&x[i];
    f32x4 hi = *(const f32x4*)&x[i + 4];
    *(u32x4*)&xb[i] = pack8(lo, hi);
}

// ------------- shared GEMM core macros ---------------------------------------
// C[M x 512] = A[M x 512] @ W (given bf16 W^T), 128x128 tile, m97 staging.

// ------------- fused QKV GEMM: 3 weights, one launch -------------------------
__global__ __launch_bounds__(256) void gemm_qkv(
    const bf16* __restrict__ A, const bf16* __restrict__ WT,
    const float* __restrict__ bqp, const float* __restrict__ bkp, const float* __restrict__ bvp,
    bf16* __restrict__ qb, bf16* __restrict__ kb, bf16* __restrict__ vT)
{
    __shared__ __align__(16) bf16 As[128 * 32];
    __shared__ __align__(16) bf16 Bs[128 * 32];
    const int tid = threadIdx.x;
    const int lane = tid & 63, wave = tid >> 6;
    const int wm = (wave >> 1) * 64, wn = (wave & 1) * 64;
    const int wsel = blockIdx.y >> 2;                  // 0=q 1=k 2=v
    const int bm = blockIdx.x * 128, bn = (blockIdx.y & 3) * 128;
    const bf16* Bt = WT + (size_t)wsel * 262144;
    const float* bias = (wsel == 0) ? bqp : (wsel == 1) ? bkp : bvp;
    const int lm = lane & 15, lq = lane >> 4;

    f32x4 acc[4][4];
#pragma unroll
    for (int i = 0; i < 4; i++)
#pragma unroll
        for (int j = 0; j < 4; j++) acc[i][j] = (f32x4){0.f, 0.f, 0.f, 0.f};

    for (int k0 = 0; k0 < 512; k0 += 32) {
        __syncthreads();
#pragma unroll
        for (int p = 0; p < 2; p++) {
            int c = p * 256 + tid;
            int r = c >> 2, kc = (c & 3) * 8;
            async16(&A[(size_t)(bm + r) * 512 + k0 + kc], &As[(p * 256 + wave * 64) * 8]);
            async16(&Bt[(size_t)(bn + r) * 512 + k0 + kc], &Bs[(p * 256 + wave * 64) * 8]);
        }
        __syncthreads();
        u32x4 af[4], bfr[4];
#pragma unroll
        for (int i = 0; i < 4; i++) af[i] = *(const u32x4*)&As[(wm + i * 16 + lm) * 32 + lq * 8];
#pragma unroll
        for (int j = 0; j < 4; j++) bfr[j] = *(const u32x4*)&Bs[(wn + j * 16 + lm) * 32 + lq * 8];
#pragma unroll
        for (int i = 0; i < 4; i++)
#pragma unroll
            for (int j = 0; j < 4; j++) acc[i][j] = mfma16(af[i], bfr[j], acc[i][j]);
    }

#pragma unroll
    for (int i = 0; i < 4; i++) {
#pragma unroll
        for (int j = 0; j < 4; j++) {
            int col = bn + wn + j * 16 + lm;
            float bv = bias[col];
#pragma unroll
            for (int r = 0; r < 4; r++) {
                int row = bm + wm + i * 16 + lq * 4 + r;
                float cv = acc[i][j][r] + bv;
                if (wsel == 0) {
                    qb[(size_t)row * 512 + col] = __float2bfloat16(cv * 0.18033688f); // log2e/8
                } else if (wsel == 1) {
                    kb[(size_t)row * 512 + col] = __float2bfloat16(cv);
                } else {
                    int bt = row >> 10, node = row & 1023;
                    int hh = col >> 6, d = col & 63;
                    vT[((size_t)((bt * 8 + hh) * 64 + d)) * 1024 + node] = __float2bfloat16(cv);
                }
            }
        }
    }
}

// ------------- FFN GEMM (RELU or plain) --------------------------------------
template <bool RELU>
__global__ __launch_bounds__(256) void gemm_bt(
    const bf16* __restrict__ A, const bf16* __restrict__ Bt,
    const float* __restrict__ bias, bf16* __restrict__ C)
{
    __shared__ __align__(16) bf16 As[128 * 32];
    __shared__ __align__(16) bf16 Bs[128 * 32];
    const int tid = threadIdx.x;
    const int lane = tid & 63, wave = tid >> 6;
    const int wm = (wave >> 1) * 64, wn = (wave & 1) * 64;
    const int bm = blockIdx.x * 128, bn = blockIdx.y * 128;
    const int lm = lane & 15, lq = lane >> 4;

    f32x4 acc[4][4];
#pragma unroll
    for (int i = 0; i < 4; i++)
#pragma unroll
        for (int j = 0; j < 4; j++) acc[i][j] = (f32x4){0.f, 0.f, 0.f, 0.f};

    for (int k0 = 0; k0 < 512; k0 += 32) {
        __syncthreads();
#pragma unroll
        for (int p = 0; p < 2; p++) {
            int c = p * 256 + tid;
            int r = c >> 2, kc = (c & 3) * 8;
            async16(&A[(size_t)(bm + r) * 512 + k0 + kc], &As[(p * 256 + wave * 64) * 8]);
            async16(&Bt[(size_t)(bn + r) * 512 + k0 + kc], &Bs[(p * 256 + wave * 64) * 8]);
        }
        __syncthreads();
        u32x4 af[4], bfr[4];
#pragma unroll
        for (int i = 0; i < 4; i++) af[i] = *(const u32x4*)&As[(wm + i * 16 + lm) * 32 + lq * 8];
#pragma unroll
        for (int j = 0; j < 4; j++) bfr[j] = *(const u32x4*)&Bs[(wn + j * 16 + lm) * 32 + lq * 8];
#pragma unroll
        for (int i = 0; i < 4; i++)
#pragma unroll
            for (int j = 0; j < 4; j++) acc[i][j] = mfma16(af[i], bfr[j], acc[i][j]);
    }

#pragma unroll
    for (int i = 0; i < 4; i++) {
#pragma unroll
        for (int j = 0; j < 4; j++) {
            int col = bn + wn + j * 16 + lm;
            float bv = bias[col];
#pragma unroll
            for (int r = 0; r < 4; r++) {
                int row = bm + wm + i * 16 + lq * 4 + r;
                float cv = acc[i][j][r] + bv;
                if (RELU) cv = fmaxf(cv, 0.f);
                C[(size_t)row * 512 + col] = __float2bfloat16(cv);
            }
        }
    }
}

// ------------- flash attention (no-max softmax, S^T trick) -------------------
// q (pre-scaled by log2e/8), k: [16384 x 512] bf16 ; vT: [(g)*64+d][1024] bf16
// o: [16384 x 512] f32
__global__ __launch_bounds__(256) void attn_kernel(
    const bf16* __restrict__ q, const bf16* __restrict__ k,
    const bf16* __restrict__ vT, float* __restrict__ o)
{
    constexpr int KP = 72;   // 144 B row stride: 16-B aligned, stride 36 words -> 2-way (free)
    constexpr int VP = 72;   // same (80 was 4-way conflicted: 40 words = 8 mod 32)
    __shared__ __align__(16) bf16 Ks[64 * KP];        // [key][d]
    __shared__ __align__(16) bf16 Vs[64 * VP];        // [d][key]
    __shared__ __align__(16) bf16 Ps[4][32 * VP];     // per-wave [q][key]

    const int tid = threadIdx.x, lane = tid & 63, wave = tid >> 6;
    const int group = blockIdx.y;          // bt*8 + h
    const int bt = group >> 3, hh = group & 7;
    const int lm = lane & 15, lq = lane >> 4;
    const int qrow0 = bt * 1024 + blockIdx.x * 128 + wave * 32;

    u32x4 qf[2][2];
#pragma unroll
    for (int tm = 0; tm < 2; tm++)
#pragma unroll
        for (int kk = 0; kk < 2; kk++)
            qf[tm][kk] = *(const u32x4*)&q[(size_t)(qrow0 + tm * 16 + lm) * 512 + hh * 64 + kk * 32 + lq * 8];

    f32x4 accO[2][4];
#pragma unroll
    for (int tm = 0; tm < 2; tm++)
#pragma unroll
        for (int tn = 0; tn < 4; tn++) accO[tm][tn] = (f32x4){0.f, 0.f, 0.f, 0.f};
    float part[2] = {0.f, 0.f};

    for (int kt = 0; kt < 16; kt++) {
        __syncthreads();   // prior S/PV reads of Ks/Vs done
#pragma unroll
        for (int p = 0; p < 2; p++) {
            int c = p * 256 + tid;
            int row = c >> 3, e8 = (c & 7) * 8;
            *(u32x4*)&Ks[row * KP + e8] =
                *(const u32x4*)&k[(size_t)(bt * 1024 + kt * 64 + row) * 512 + hh * 64 + e8];
            *(u32x4*)&Vs[row * VP + e8] =
                *(const u32x4*)&vT[(size_t)(group * 64 + row) * 1024 + kt * 64 + e8];
        }
        __syncthreads();

        // S^T tiles: A=K (m=key), B=Q (n=q); C-frag rows = 4 consecutive keys
#pragma unroll
        for (int tk = 0; tk < 4; tk++) {
            u32x4 kf0 = *(const u32x4*)&Ks[(tk * 16 + lm) * KP + lq * 8];
            u32x4 kf1 = *(const u32x4*)&Ks[(tk * 16 + lm) * KP + 32 + lq * 8];
#pragma unroll
            for (int tm = 0; tm < 2; tm++) {
                f32x4 st = (f32x4){0.f, 0.f, 0.f, 0.f};
                st = mfma16(kf0, qf[tm][0], st);
                st = mfma16(kf1, qf[tm][1], st);
                float p0 = __builtin_amdgcn_exp2f(st[0]);
                float p1 = __builtin_amdgcn_exp2f(st[1]);
                float p2 = __builtin_amdgcn_exp2f(st[2]);
                float p3 = __builtin_amdgcn_exp2f(st[3]);
                part[tm] += (p0 + p1) + (p2 + p3);
                unsigned lo = rne2(p0, p1), hi = rne2(p2, p3);
                unsigned long long pk = ((unsigned long long)hi << 32) | lo;
                // P[q=tm*16+lm][key=tk*16+lq*4 .. +3]  (wave-private, no barrier)
                *(unsigned long long*)&Ps[wave][(tm * 16 + lm) * VP + tk * 16 + lq * 4] = pk;
            }
        }

        // O += P V   (A=P from LDS, B=V^T)
#pragma unroll
        for (int kc = 0; kc < 2; kc++) {
            u32x4 pf[2], vf[4];
#pragma unroll
            for (int tm = 0; tm < 2; tm++)
                pf[tm] = *(const u32x4*)&Ps[wave][(tm * 16 + lm) * VP + kc * 32 + lq * 8];
#pragma unroll
            for (int tn = 0; tn < 4; tn++)
                vf[tn] = *(const u32x4*)&Vs[(tn * 16 + lm) * VP + kc * 32 + lq * 8];
#pragma unroll
            for (int tm = 0; tm < 2; tm++)
#pragma unroll
                for (int tn = 0; tn < 4; tn++)
                    accO[tm][tn] = mfma16(pf[tm], vf[tn], accO[tm][tn]);
        }
    }

    // final l reduction (across quads) and normalized store
#pragma unroll
    for (int tm = 0; tm < 2; tm++) {
        part[tm] += __shfl_xor(part[tm], 16);
        part[tm] += __shfl_xor(part[tm], 32);
    }
#pragma unroll
    for (int tm = 0; tm < 2; tm++)
#pragma unroll
        for (int r = 0; r < 4; r++) {
            float l = __shfl(part[tm], lq * 4 + r);   // lane lq*4+r holds l for q-row lq*4+r
            float linv = 1.0f / l;
#pragma unroll
            for (int tn = 0; tn < 4; tn++) {
                int row = qrow0 + tm * 16 + lq * 4 + r;
                int col = hh * 64 + tn * 16 + lm;
                o[(size_t)row * 512 + col] = accO[tm][tn][r] * linv;
            }
        }
}

// ------------- LayerNorm (one wave per 512-el row) ---------------------------
template <bool AF32, bool RES, bool OF32>
__global__ __launch_bounds__(256) void ln_kernel(
    const void* __restrict__ a, const float* __restrict__ res,
    const float* __restrict__ g, const float* __restrict__ bb, void* __restrict__ out)
{
    int row = blockIdx.x * 4 + (threadIdx.x >> 6);
    int lane = threadIdx.x & 63;
    size_t base = (size_t)row * 512 + lane * 8;
    int cbase = lane * 8;

    float x8[8];
    if (AF32) {
        const float* af = (const float*)a;
        f32x4 lo = *(const f32x4*)&af[base];
        f32x4 hi = *(const f32x4*)&af[base + 4];
#pragma unroll
        for (int i = 0; i < 4; i++) { x8[i] = lo[i]; x8[4 + i] = hi[i]; }
    } else {
        bf8 av = __builtin_bit_cast(bf8, *(const u32x4*)&((const bf16*)a)[base]);
#pragma unroll
        for (int i = 0; i < 8; i++) x8[i] = __bfloat162float(av.h[i]);
    }
    if (RES) {
        f32x4 lo = *(const f32x4*)&res[base];
        f32x4 hi = *(const f32x4*)&res[base + 4];
#pragma unroll
        for (int i = 0; i < 4; i++) { x8[i] += lo[i]; x8[4 + i] += hi[i]; }
    }

    float s = 0.f, s2 = 0.f;
#pragma unroll
    for (int i = 0; i < 8; i++) { s += x8[i]; s2 += x8[i] * x8[i]; }
#pragma unroll
    for (int off = 1; off < 64; off <<= 1) {
        s += __shfl_xor(s, off);
        s2 += __shfl_xor(s2, off);
    }
    float mean = s * (1.f / 512.f);
    float var = s2 * (1.f / 512.f) - mean * mean;
    float rstd = rsqrtf(var + 1e-5f);

    f32x4 g0 = *(const f32x4*)&g[cbase], g1 = *(const f32x4*)&g[cbase + 4];
    f32x4 b0 = *(const f32x4*)&bb[cbase], b1v = *(const f32x4*)&bb[cbase + 4];
    float y[8];
#pragma unroll
    for (int i = 0; i < 4; i++) {
        y[i] = (x8[i] - mean) * rstd * g0[i] + b0[i];
        y[4 + i] = (x8[4 + i] - mean) * rstd * g1[i] + b1v[i];
    }
    if (OF32) {
        float* op = (float*)out;
        *(f32x4*)&op[base] = (f32x4){y[0], y[1], y[2], y[3]};
        *(f32x4*)&op[base + 4] = (f32x4){y[4], y[5], y[6], y[7]};
    } else {
        bf8 ov;
#pragma unroll
        for (int i = 0; i < 8; i++) ov.h[i] = __float2bfloat16(y[i]);
        *(u32x4*)&((bf16*)out)[base] = __builtin_bit_cast(u32x4, ov);
    }
}

// ------------- launch --------------------------------------------------------
extern "C" void kernel_launch(void* const* d_in, const int* in_sizes, int n_in,
                              void* d_out, int out_size, void* d_ws, size_t ws_size,
                              hipStream_t stream)
{
    const float* x    = (const float*)d_in[0];
    const float* Wq   = (const float*)d_in[1];
    const float* bq   = (const float*)d_in[2];
    const float* Wk   = (const float*)d_in[3];
    const float* bk   = (const float*)d_in[4];
    const float* Wv   = (const float*)d_in[5];
    const float* bv   = (const float*)d_in[6];
    const float* ln_g = (const float*)d_in[7];
    const float* ln_b = (const float*)d_in[8];
    const float* W1   = (const float*)d_in[9];
    const float* b1   = (const float*)d_in[10];
    const float* W2   = (const float*)d_in[11];
    const float* b2   = (const float*)d_in[12];
    const float* lnffg = (const float*)d_in[13];
    const float* lnffb = (const float*)d_in[14];
    float* out = (float*)d_out;

    bf16* ws = (bf16*)d_ws;
    bf16* WT = ws;                        // 5 * 262144 bf16
    bf16* qb = ws + 5 * 262144;           // 8388608 bf16 each below
    bf16* kb = qb + 8388608;
    bf16* vT = kb + 8388608;
    bf16* vl = qb;                        // reuse (q dead after attention)
    bf16* f1 = kb;                        // reuse (k dead after attention)
    bf16* f2 = vT;                        // reuse (v dead after attention)
    bf16* xb = (bf16*)d_out;              // 16.7MB scratch; dead before attention writes O

    prep_weights<<<dim3(1024, 5), 256, 0, stream>>>(Wq, Wk, Wv, W1, W2, WT);
    prep_x<<<4096, 256, 0, stream>>>(x, xb);

    gemm_qkv<<<dim3(128, 12), 256, 0, stream>>>(xb, WT, bq, bk, bv, qb, kb, vT);

    attn_kernel<<<dim3(8, 128), 256, 0, stream>>>(qb, kb, vT, out);

    ln_kernel<true, true, false><<<4096, 256, 0, stream>>>(out, x, ln_g, ln_b, vl);

    dim3 gg(128, 4);
    gemm_bt<true> <<<gg, 256, 0, stream>>>(vl, WT + 3 * 262144, b1, f1);
    gemm_bt<false><<<gg, 256, 0, stream>>>(f1, WT + 4 * 262144, b2, f2);

    ln_kernel<false, false, true><<<4096, 256, 0, stream>>>(f2, nullptr, lnffg, lnffb, out);
}